// Round 1
// baseline (126.315 us; speedup 1.0000x reference)
//
#include <hip/hip_runtime.h>
#include <hip/hip_bf16.h>
#include <math.h>

#define CHN 192
#define BATCHN 65536
#define NBLOCKS 2048
#define ROWS_PER_BLOCK (BATCHN / NBLOCKS)   // 32

// ---- fast device math -------------------------------------------------------
__device__ __forceinline__ float fast_rcp(float x) {
    return __builtin_amdgcn_rcpf(x);        // v_rcp_f32, ~1 ulp
}

// tanh(y) = sign(y) * (1 - 2/(exp(2|y|)+1)); exp overflow -> inf -> rcp -> 0 -> 1. Safe.
__device__ __forceinline__ float fast_tanh(float y) {
    float ay = fabsf(y);
    float e  = __expf(2.0f * ay);           // v_exp_f32 after mul by log2e
    float r  = 1.0f - 2.0f * fast_rcp(e + 1.0f);
    return copysignf(r, y);
}

// sigmoid(s) = 1/(1+exp(-s)); s << 0 -> exp -> inf -> rcp -> 0. Safe.
__device__ __forceinline__ float fast_sigmoid(float s) {
    return fast_rcp(1.0f + __expf(-s));
}

// accurate softplus for the once-per-block weight transform
__device__ __forceinline__ float softplus_acc(float h) {
    if (h > 20.0f) return h;
    return log1pf(expf(h));
}

// ---- per-channel weights in registers --------------------------------------
struct WReg {
    float W0[3], B0[3], T0[3];
    float W1[9], B1[3], T1[3];
    float W2[9], B2[3], T2[3];
    float W3[3], B3;
};

__device__ __forceinline__ float cdf_eval(const WReg& w, float u) {
    float v[3];
#pragma unroll
    for (int i = 0; i < 3; ++i) {
        float t = fmaf(u, w.W0[i], w.B0[i]);
        v[i] = fmaf(w.T0[i], fast_tanh(t), t);
    }
    float z[3];
#pragma unroll
    for (int p = 0; p < 3; ++p) {
        float t = w.B1[p];
#pragma unroll
        for (int i = 0; i < 3; ++i) t = fmaf(v[i], w.W1[i * 3 + p], t);
        z[p] = fmaf(w.T1[p], fast_tanh(t), t);
    }
    float y[3];
#pragma unroll
    for (int p = 0; p < 3; ++p) {
        float t = w.B2[p];
#pragma unroll
        for (int i = 0; i < 3; ++i) t = fmaf(z[i], w.W2[i * 3 + p], t);
        y[p] = fmaf(w.T2[p], fast_tanh(t), t);
    }
    float s = w.B3;
#pragma unroll
    for (int i = 0; i < 3; ++i) s = fmaf(y[i], w.W3[i], s);
    return fast_sigmoid(s);
}

__global__ __launch_bounds__(CHN) void density_kernel(
    const float* __restrict__ x,
    const float* __restrict__ a0, const float* __restrict__ a1, const float* __restrict__ a2,
    const float* __restrict__ b0, const float* __restrict__ b1, const float* __restrict__ b2,
    const float* __restrict__ b3,
    const float* __restrict__ H0, const float* __restrict__ H1, const float* __restrict__ H2,
    const float* __restrict__ H3,
    float* __restrict__ out)
{
    const int c = threadIdx.x;          // thread <-> channel, 192 threads/block

    // ---- once per block: transform weights into registers ----
    WReg w;
#pragma unroll
    for (int i = 0; i < 3; ++i) {
        w.T0[i] = tanhf(a0[c * 3 + i]);
        w.T1[i] = tanhf(a1[c * 3 + i]);
        w.T2[i] = tanhf(a2[c * 3 + i]);
        w.B0[i] = b0[c * 3 + i];
        w.B1[i] = b1[c * 3 + i];
        w.B2[i] = b2[c * 3 + i];
        w.W0[i] = softplus_acc(H0[c * 3 + i]);   // H0: (C,1,3)
        w.W3[i] = softplus_acc(H3[c * 3 + i]);   // H3: (C,3,1)
    }
#pragma unroll
    for (int i = 0; i < 9; ++i) {
        w.W1[i] = softplus_acc(H1[c * 9 + i]);   // (C,3,3) row-major [i][p]
        w.W2[i] = softplus_acc(H2[c * 9 + i]);
    }
    w.B3 = b3[c];

    // ---- main loop over this block's batch rows (coalesced: lane = channel) ----
    const int b_start = blockIdx.x * ROWS_PER_BLOCK;
    const int b_end   = b_start + ROWS_PER_BLOCK;
    for (int b = b_start; b < b_end; ++b) {
        const int idx = b * CHN + c;
        float xv = x[idx];
        float p  = cdf_eval(w, xv + 0.5f) - cdf_eval(w, xv - 0.5f);
        out[idx] = p;
    }
}

extern "C" void kernel_launch(void* const* d_in, const int* in_sizes, int n_in,
                              void* d_out, int out_size, void* d_ws, size_t ws_size,
                              hipStream_t stream) {
    const float* x  = (const float*)d_in[0];
    const float* a0 = (const float*)d_in[1];
    const float* a1 = (const float*)d_in[2];
    const float* a2 = (const float*)d_in[3];
    const float* b0 = (const float*)d_in[4];
    const float* b1 = (const float*)d_in[5];
    const float* b2 = (const float*)d_in[6];
    const float* b3 = (const float*)d_in[7];
    const float* H0 = (const float*)d_in[8];
    const float* H1 = (const float*)d_in[9];
    const float* H2 = (const float*)d_in[10];
    const float* H3 = (const float*)d_in[11];
    float* out = (float*)d_out;

    density_kernel<<<NBLOCKS, CHN, 0, stream>>>(x, a0, a1, a2, b0, b1, b2, b3,
                                                H0, H1, H2, H3, out);
}